// Round 1
// baseline (655.608 us; speedup 1.0000x reference)
//
#include <hip/hip_runtime.h>
#include <hip/hip_bf16.h>
#include <math.h>

// Problem constants (fixed by the reference)
#define MV   100000          // voxels
#define NQ   8192            // queries
#define KN   32              // neighbors per query
#define CH   256             // channels
#define NH   8               // heads
#define DHD  32              // head dim
#define FFD  512             // FF hidden
#define NG   (NQ*KN)         // 262144 gathered rows
#define QPW  37              // 15+15+7 rel-pos columns per head (q-side)
#define QPN  (NH*QPW)        // 296

typedef __bf16 bf16x8 __attribute__((ext_vector_type(8)));
typedef float  f32x4  __attribute__((ext_vector_type(4)));

__device__ __forceinline__ float bf2f(unsigned short u) {
    return __uint_as_float(((unsigned int)u) << 16);
}
__device__ __forceinline__ unsigned short f2bf(float f) {
    unsigned int x = __float_as_uint(f);
    unsigned int r = x + 0x7FFFu + ((x >> 16) & 1u);   // RNE
    return (unsigned short)(r >> 16);
}

// ---------------------------------------------------------------------------
// k_detect_mask: gather_mask is bool in the reference; harness may ship it as
// int32 (0/1) or as raw 1-byte bools. If int32, every byte at offset%4!=0 of
// the first NG bytes is zero. flag=1 -> byte layout, flag=0 -> int32 layout.
// ---------------------------------------------------------------------------
__global__ __launch_bounds__(256) void k_detect_mask(const unsigned char* __restrict__ raw,
                                                     int* __restrict__ flag) {
    __shared__ int any;
    if (threadIdx.x == 0) any = 0;
    __syncthreads();
    const uint4* p = (const uint4*)raw;             // first NG bytes = NG/16 uint4
    int found = 0;
    for (int i = threadIdx.x; i < NG / 16; i += 256) {
        uint4 v = p[i];
        if ((v.x | v.y | v.z | v.w) & 0xFFFFFF00u) found = 1;
    }
    if (found) any = 1;
    __syncthreads();
    if (threadIdx.x == 0) flag[0] = any;
}

// ---------------------------------------------------------------------------
// k_prep: materialize int mask (layout-adaptive) + build transposed bf16
// weight w_kv_t[512][256]: cols 0..255 = w_k columns, 256..511 = w_v columns.
// w_kv_t[col][j] = W[j][col].
// ---------------------------------------------------------------------------
__global__ __launch_bounds__(256) void k_prep(const float* __restrict__ w_k,
                                              const float* __restrict__ w_v,
                                              const void* __restrict__ mask_raw,
                                              const int* __restrict__ flag,
                                              unsigned short* __restrict__ w_kv_t,
                                              int* __restrict__ mask_i) {
    int idx = blockIdx.x * 256 + threadIdx.x;       // grid 1024 -> 262144
    int byteLayout = flag[0];
    if (idx < NG) {
        int mv = byteLayout ? (int)((const unsigned char*)mask_raw)[idx]
                            : ((const int*)mask_raw)[idx];
        mask_i[idx] = (mv != 0) ? 1 : 0;
    }
    if (idx < 512 * 256) {
        int col = idx >> 8, j = idx & 255;
        float v = (col < 256) ? w_k[j * 256 + col] : w_v[j * 256 + (col - 256)];
        w_kv_t[idx] = f2bf(v);                      // idx == col*256 + j
    }
}

// ---------------------------------------------------------------------------
// k_ln1: LayerNorm over all M voxel rows -> bf16. One wave per row.
// ---------------------------------------------------------------------------
__global__ __launch_bounds__(256) void k_ln1(const float* __restrict__ vox,
                                             const float* __restrict__ g,
                                             const float* __restrict__ b,
                                             unsigned short* __restrict__ ln_x) {
    int wid = threadIdx.x >> 6, lane = threadIdx.x & 63;
    int row = blockIdx.x * 4 + wid;
    if (row >= MV) return;
    const float4 v = *(const float4*)(vox + (size_t)row * CH + lane * 4);
    float s  = v.x + v.y + v.z + v.w;
    float sq = v.x * v.x + v.y * v.y + v.z * v.z + v.w * v.w;
    #pragma unroll
    for (int off = 1; off < 64; off <<= 1) {
        s  += __shfl_xor(s,  off);
        sq += __shfl_xor(sq, off);
    }
    float mu  = s * (1.f / CH);
    float var = sq * (1.f / CH) - mu * mu;
    float rs  = rsqrtf(var + 1e-5f);
    float4 gv = *(const float4*)(g + lane * 4);
    float4 bv = *(const float4*)(b + lane * 4);
    ushort4 o;
    o.x = f2bf((v.x - mu) * rs * gv.x + bv.x);
    o.y = f2bf((v.y - mu) * rs * gv.y + bv.y);
    o.z = f2bf((v.z - mu) * rs * gv.z + bv.z);
    o.w = f2bf((v.w - mu) * rs * gv.w + bv.w);
    *(ushort4*)(ln_x + (size_t)row * CH + lane * 4) = o;
}

// ---------------------------------------------------------------------------
// k_q: per 8-query block: q_in = ln_x[qi] + relu(coords@w_pos + b_pos);
// q = q_in@w_q + b_q (fp32); then q-side rel-pos table qp[n][h][37].
// ---------------------------------------------------------------------------
__global__ __launch_bounds__(256) void k_q(const unsigned short* __restrict__ ln_x,
                                           const float* __restrict__ coords,
                                           const int* __restrict__ qidx,
                                           const float* __restrict__ w_pos,
                                           const float* __restrict__ b_pos,
                                           const float* __restrict__ w_q,
                                           const float* __restrict__ b_q,
                                           const float* __restrict__ pos_qx,
                                           const float* __restrict__ pos_qy,
                                           const float* __restrict__ pos_qz,
                                           float* __restrict__ qout,
                                           float* __restrict__ qp) {
    __shared__ float qin_s[8 * CH];
    __shared__ float q_s[8 * CH];
    int c = threadIdx.x;
    int nb = blockIdx.x * 8;
    float wp0 = w_pos[c], wp1 = w_pos[CH + c], wp2 = w_pos[2 * CH + c], bp = b_pos[c];
    #pragma unroll
    for (int qq = 0; qq < 8; qq++) {
        int n = nb + qq;
        float p = bp + coords[n * 3] * wp0 + coords[n * 3 + 1] * wp1 + coords[n * 3 + 2] * wp2;
        p = fmaxf(p, 0.f);
        int qi = qidx[n];
        qin_s[qq * CH + c] = bf2f(ln_x[(size_t)qi * CH + c]) + p;
    }
    __syncthreads();
    float acc[8];
    float bq = b_q[c];
    #pragma unroll
    for (int qq = 0; qq < 8; qq++) acc[qq] = bq;
    #pragma unroll 4
    for (int j = 0; j < CH; j++) {
        float w = w_q[j * CH + c];
        #pragma unroll
        for (int qq = 0; qq < 8; qq++) acc[qq] += qin_s[qq * CH + j] * w;
    }
    #pragma unroll
    for (int qq = 0; qq < 8; qq++) {
        qout[(size_t)(nb + qq) * CH + c] = acc[qq];
        q_s[qq * CH + c] = acc[qq];
    }
    __syncthreads();
    for (int t = threadIdx.x; t < 8 * QPN; t += 256) {
        int qq = t / QPN, u = t % QPN;
        int h = u / QPW, r = u % QPW;
        const float* tab; int rr, R;
        if (r < 15)      { tab = pos_qx; rr = r;      R = 15; }
        else if (r < 30) { tab = pos_qy; rr = r - 15; R = 15; }
        else             { tab = pos_qz; rr = r - 30; R = 7;  }
        float a = 0.f;
        const float* qrow = q_s + qq * CH + h * DHD;
        #pragma unroll
        for (int d = 0; d < DHD; d++) a += qrow[d] * tab[(h * DHD + d) * R + rr];
        qp[(size_t)(nb + qq) * QPN + u] = a;
    }
}

// ---------------------------------------------------------------------------
// k_gemm<MODE>: gathered-row GEMM over the 262144 (n,k) rows.
//   A[128 x 256]  = ln_x[gather_indices[...]] (zeroed where masked), bf16
//   B              = w_k (MODE 0) or w_v (MODE 1) columns of w_kv_t
//   MODE 0: store k = A@w_k + b_k as bf16 [NG][256]
//   MODE 1: epilogue computes attnout[n][c] = sum_k attn[n,h(c),k]*v[k][c] + b_v[c]
// Tile: 128 rows x 64 cols, 4 waves (wave w = rows w*32..w*32+31 = query w's
// 32 neighbors when MODE 1), K-loop 8 steps of 32, mfma_f32_16x16x32_bf16.
// ---------------------------------------------------------------------------
template <int MODE>
__global__ __launch_bounds__(256) void k_gemm(const unsigned short* __restrict__ ln_x,
                                              const int* __restrict__ gidx,
                                              const int* __restrict__ mask_i,
                                              const unsigned short* __restrict__ w_kv_t,
                                              const float* __restrict__ bias,
                                              const float* __restrict__ attn,
                                              unsigned short* __restrict__ kout,
                                              float* __restrict__ attnout) {
    __shared__ __align__(16) unsigned short As[128 * 32];   // row-major, stride 32
    __shared__ __align__(16) unsigned short Bt[64 * 40];    // col-major, stride 40 (80B, 16B-aligned)
    __shared__ float attn_s[4 * 256];                       // MODE 1 only
    int tid = threadIdx.x;
    int w = tid >> 6, l = tid & 63;
    int rowbase = blockIdx.y * 128;
    int col0_w = blockIdx.x * 64 + (MODE ? 256 : 0);        // column base in w_kv_t space

    // A staging assignment: chunk c (16B) -> row c/4, quarter c%4; thread owns
    // chunks tid and tid+256 -> conflict-free linear LDS writes.
    int r0 = tid >> 2, qt = tid & 3;
    int g0 = gidx[rowbase + r0];
    int m0 = mask_i[rowbase + r0];
    int g1 = gidx[rowbase + 64 + r0];
    int m1 = mask_i[rowbase + 64 + r0];
    const unsigned short* a0p = ln_x + (size_t)g0 * CH + qt * 8;
    const unsigned short* a1p = ln_x + (size_t)g1 * CH + qt * 8;

    if (MODE) {
        for (int i = tid; i < 1024; i += 256)
            attn_s[i] = attn[(size_t)blockIdx.y * 1024 + i];   // 4 queries' [H][K]
    }

    f32x4 acc[2][4];
    #pragma unroll
    for (int mt = 0; mt < 2; mt++)
        #pragma unroll
        for (int nt = 0; nt < 4; nt++)
            acc[mt][nt] = (f32x4){0.f, 0.f, 0.f, 0.f};

    const int ml = l & 15, qd = l >> 4;
    const uint4 z4 = {0u, 0u, 0u, 0u};
    for (int kk = 0; kk < CH; kk += 32) {
        __syncthreads();
        uint4 v0 = m0 ? z4 : *(const uint4*)(a0p + kk);
        uint4 v1 = m1 ? z4 : *(const uint4*)(a1p + kk);
        *(uint4*)(As + tid * 8)        = v0;
        *(uint4*)(As + 2048 + tid * 8) = v1;
        {
            int cl = tid >> 2, sg = tid & 3;
            uint4 bv = *(const uint4*)(w_kv_t + (size_t)(col0_w + cl) * CH + kk + sg * 8);
            *(uint4*)(Bt + cl * 40 + sg * 8) = bv;
        }
        __syncthreads();
        bf16x8 a0 = *(const bf16x8*)(As + (w * 32 + ml) * 32 + qd * 8);
        bf16x8 a1 = *(const bf16x8*)(As + (w * 32 + 16 + ml) * 32 + qd * 8);
        #pragma unroll
        for (int nt = 0; nt < 4; nt++) {
            bf16x8 bb = *(const bf16x8*)(Bt + (nt * 16 + ml) * 40 + qd * 8);
            acc[0][nt] = __builtin_amdgcn_mfma_f32_16x16x32_bf16(a0, bb, acc[0][nt], 0, 0, 0);
            acc[1][nt] = __builtin_amdgcn_mfma_f32_16x16x32_bf16(a1, bb, acc[1][nt], 0, 0, 0);
        }
    }

    if (MODE == 0) {
        int colg0 = blockIdx.x * 64;
        #pragma unroll
        for (int nt = 0; nt < 4; nt++) {
            int col = colg0 + nt * 16 + ml;
            float bk = bias[col];
            #pragma unroll
            for (int mt = 0; mt < 2; mt++) {
                int rl = w * 32 + mt * 16 + qd * 4;
                #pragma unroll
                for (int i = 0; i < 4; i++)
                    kout[(size_t)(rowbase + rl + i) * CH + col] = f2bf(acc[mt][nt][i] + bk);
            }
        }
    } else {
        // wave w == query (blockIdx.y*4 + w); its 32 rows are that query's k's
        #pragma unroll
        for (int nt = 0; nt < 4; nt++) {
            int col = blockIdx.x * 64 + nt * 16 + ml;    // 0..255
            int h = col >> 5;
            float ps = 0.f;
            #pragma unroll
            for (int mt = 0; mt < 2; mt++)
                #pragma unroll
                for (int i = 0; i < 4; i++) {
                    int kkk = mt * 16 + qd * 4 + i;
                    ps += attn_s[w * 256 + (h << 5) + kkk] * acc[mt][nt][i];
                }
            ps += __shfl_xor(ps, 16);
            ps += __shfl_xor(ps, 32);
            if (qd == 0)
                attnout[(size_t)(blockIdx.y * 4 + w) * CH + col] = ps + bias[col];
        }
    }
}

// ---------------------------------------------------------------------------
// k_attn: logits = q.k * DH^-0.5 + q-side bias (gathered qp) + k-side bias
// (dot k with staged pos_k tables at rel idx); mask -> -1e9; softmax over K.
// 4 queries per block; thread = (h, k).
// ---------------------------------------------------------------------------
__global__ __launch_bounds__(256) void k_attn(const float* __restrict__ qbuf,
                                              const float* __restrict__ qp,
                                              const unsigned short* __restrict__ kmat,
                                              const int* __restrict__ mask_i,
                                              const int* __restrict__ rel_x,
                                              const int* __restrict__ rel_y,
                                              const int* __restrict__ rel_z,
                                              const float* __restrict__ pos_kx,
                                              const float* __restrict__ pos_ky,
                                              const float* __restrict__ pos_kz,
                                              float* __restrict__ attn) {
    __shared__ float pos_s[9472];     // [x:3840][y:3840][z:1792]
    __shared__ float q_s[1024];
    __shared__ float qp_s[4 * QPN];
    int tid = threadIdx.x;
    int qb = blockIdx.x * 4;
    for (int i = tid; i < 3840; i += 256) pos_s[i] = pos_kx[i];
    for (int i = tid; i < 3840; i += 256) pos_s[3840 + i] = pos_ky[i];
    for (int i = tid; i < 1792; i += 256) pos_s[7680 + i] = pos_kz[i];
    for (int i = tid; i < 1024; i += 256) q_s[i] = qbuf[(size_t)qb * CH + i];
    for (int i = tid; i < 4 * QPN; i += 256) qp_s[i] = qp[(size_t)qb * QPN + i];
    __syncthreads();
    int h = tid >> 5, k = tid & 31;
    const float scale = 0.17677669529663687f;   // 32^-0.5
    for (int qq = 0; qq < 4; qq++) {
        int n = qb + qq;
        int gi = n * KN + k;
        int mk = mask_i[gi];
        int rx = rel_x[gi], ry = rel_y[gi], rz = rel_z[gi];
        const uint4* kp = (const uint4*)(kmat + (size_t)gi * CH + h * DHD);
        float kv[32];
        #pragma unroll
        for (int j = 0; j < 4; j++) {
            uint4 u = kp[j];
            kv[j * 8 + 0] = bf2f((unsigned short)(u.x & 0xFFFF));
            kv[j * 8 + 1] = bf2f((unsigned short)(u.x >> 16));
            kv[j * 8 + 2] = bf2f((unsigned short)(u.y & 0xFFFF));
            kv[j * 8 + 3] = bf2f((unsigned short)(u.y >> 16));
            kv[j * 8 + 4] = bf2f((unsigned short)(u.z & 0xFFFF));
            kv[j * 8 + 5] = bf2f((unsigned short)(u.z >> 16));
            kv[j * 8 + 6] = bf2f((unsigned short)(u.w & 0xFFFF));
            kv[j * 8 + 7] = bf2f((unsigned short)(u.w >> 16));
        }
        float s1 = 0.f, s2 = 0.f;
        const float* qrow = q_s + qq * CH + h * DHD;
        const float* px = pos_s + h * 480 + rx;
        const float* py = pos_s + 3840 + h * 480 + ry;
        const float* pz = pos_s + 7680 + h * 224 + rz;
        #pragma unroll
        for (int d = 0; d < 32; d++) {
            s1 += kv[d] * qrow[d];
            s2 += kv[d] * (px[d * 15] + py[d * 15] + pz[d * 7]);
        }
        float lg = s1 * scale + s2
                 + qp_s[qq * QPN + h * QPW + rx]
                 + qp_s[qq * QPN + h * QPW + 15 + ry]
                 + qp_s[qq * QPN + h * QPW + 30 + rz];
        if (mk) lg = -1e9f;
        float mx = lg;
        #pragma unroll
        for (int off = 1; off <= 16; off <<= 1) mx = fmaxf(mx, __shfl_xor(mx, off));
        float e = __expf(lg - mx);
        float sm = e;
        #pragma unroll
        for (int off = 1; off <= 16; off <<= 1) sm += __shfl_xor(sm, off);
        attn[(size_t)n * 256 + tid] = e / sm;
    }
}

// ---------------------------------------------------------------------------
// k_proj: act = voxel[qi] + attnout@w_proj + b_proj; store act fp32 and
// LN2(act) bf16. 8 queries per block.
// ---------------------------------------------------------------------------
__global__ __launch_bounds__(256) void k_proj(const float* __restrict__ attnout,
                                              const float* __restrict__ w_proj,
                                              const float* __restrict__ b_proj,
                                              const float* __restrict__ vox,
                                              const int* __restrict__ qidx,
                                              const float* __restrict__ g2,
                                              const float* __restrict__ b2,
                                              float* __restrict__ act,
                                              unsigned short* __restrict__ actln) {
    __shared__ float xs[8 * CH];
    int c = threadIdx.x, nb = blockIdx.x * 8;
    for (int i = c; i < 8 * CH; i += 256) xs[i] = attnout[(size_t)nb * CH + i];
    __syncthreads();
    float acc[8];
    float bp = b_proj[c];
    #pragma unroll
    for (int qq = 0; qq < 8; qq++) acc[qq] = bp;
    #pragma unroll 4
    for (int j = 0; j < CH; j++) {
        float wv = w_proj[j * CH + c];
        #pragma unroll
        for (int qq = 0; qq < 8; qq++) acc[qq] += xs[qq * CH + j] * wv;
    }
    __syncthreads();                                  // xs reads done
    #pragma unroll
    for (int qq = 0; qq < 8; qq++) {
        int qi = qidx[nb + qq];
        acc[qq] += vox[(size_t)qi * CH + c];
        act[(size_t)(nb + qq) * CH + c] = acc[qq];
        xs[qq * CH + c] = acc[qq];
    }
    __syncthreads();
    int w = c >> 6, lane = c & 63;
    for (int rr = 0; rr < 2; rr++) {
        int qq = w * 2 + rr;
        const float4 v = *(const float4*)(xs + qq * CH + lane * 4);
        float s  = v.x + v.y + v.z + v.w;
        float sq = v.x * v.x + v.y * v.y + v.z * v.z + v.w * v.w;
        #pragma unroll
        for (int off = 1; off < 64; off <<= 1) {
            s  += __shfl_xor(s,  off);
            sq += __shfl_xor(sq, off);
        }
        float mu  = s * (1.f / CH);
        float var = sq * (1.f / CH) - mu * mu;
        float rs  = rsqrtf(var + 1e-5f);
        int cb = lane * 4;
        float4 gv = *(const float4*)(g2 + cb);
        float4 bv = *(const float4*)(b2 + cb);
        ushort4 o;
        o.x = f2bf((v.x - mu) * rs * gv.x + bv.x);
        o.y = f2bf((v.y - mu) * rs * gv.y + bv.y);
        o.z = f2bf((v.z - mu) * rs * gv.z + bv.z);
        o.w = f2bf((v.w - mu) * rs * gv.w + bv.w);
        *(ushort4*)(actln + (size_t)(nb + qq) * CH + cb) = o;
    }
}

// ---------------------------------------------------------------------------
// k_ff: out = act + relu(actln@w_ff1 + b_ff1)@w_ff2 + b_ff2. 8 queries/block.
// ---------------------------------------------------------------------------
__global__ __launch_bounds__(256) void k_ff(const unsigned short* __restrict__ actln,
                                            const float* __restrict__ act,
                                            const float* __restrict__ w1,
                                            const float* __restrict__ b1,
                                            const float* __restrict__ w2,
                                            const float* __restrict__ b2f,
                                            float* __restrict__ out) {
    __shared__ float xs[8 * CH];
    __shared__ float hs[8 * FFD];
    int t = threadIdx.x, nb = blockIdx.x * 8;
    for (int i = t; i < 8 * CH; i += 256) xs[i] = bf2f(actln[(size_t)nb * CH + i]);
    __syncthreads();
    float a0[8], a1[8];
    float bb0 = b1[t], bb1 = b1[t + 256];
    #pragma unroll
    for (int qq = 0; qq < 8; qq++) { a0[qq] = bb0; a1[qq] = bb1; }
    #pragma unroll 4
    for (int cc = 0; cc < CH; cc++) {
        float w1a = w1[cc * FFD + t];
        float w1b = w1[cc * FFD + t + 256];
        #pragma unroll
        for (int qq = 0; qq < 8; qq++) {
            float x = xs[qq * CH + cc];
            a0[qq] += x * w1a;
            a1[qq] += x * w1b;
        }
    }
    #pragma unroll
    for (int qq = 0; qq < 8; qq++) {
        hs[qq * FFD + t]       = fmaxf(a0[qq], 0.f);
        hs[qq * FFD + t + 256] = fmaxf(a1[qq], 0.f);
    }
    __syncthreads();
    float o[8];
    float b2v = b2f[t];
    #pragma unroll
    for (int qq = 0; qq < 8; qq++) o[qq] = b2v;
    #pragma unroll 4
    for (int f = 0; f < FFD; f++) {
        float wv = w2[f * CH + t];
        #pragma unroll
        for (int qq = 0; qq < 8; qq++) o[qq] += hs[qq * FFD + f] * wv;
    }
    #pragma unroll
    for (int qq = 0; qq < 8; qq++)
        out[(size_t)(nb + qq) * CH + t] = o[qq] + act[(size_t)(nb + qq) * CH + t];
}

// ---------------------------------------------------------------------------
extern "C" void kernel_launch(void* const* d_in, const int* in_sizes, int n_in,
                              void* d_out, int out_size, void* d_ws, size_t ws_size,
                              hipStream_t stream) {
    (void)in_sizes; (void)n_in; (void)out_size; (void)ws_size;
    const float* vox    = (const float*)d_in[0];
    const float* coords = (const float*)d_in[1];
    const int*   qidx   = (const int*)d_in[2];
    const int*   gidx   = (const int*)d_in[3];
    const void*  mraw   = d_in[4];
    const int*   rel_x  = (const int*)d_in[5];
    const int*   rel_y  = (const int*)d_in[6];
    const int*   rel_z  = (const int*)d_in[7];
    const float* w_pos  = (const float*)d_in[8];
    const float* b_pos  = (const float*)d_in[9];
    const float* w_q    = (const float*)d_in[10];
    const float* b_q    = (const float*)d_in[11];
    const float* w_k    = (const float*)d_in[12];
    const float* b_k    = (const float*)d_in[13];
    const float* w_v    = (const float*)d_in[14];
    const float* b_v    = (const float*)d_in[15];
    const float* w_proj = (const float*)d_in[16];
    const float* b_proj = (const float*)d_in[17];
    const float* ln1_g  = (const float*)d_in[18];
    const float* ln1_b  = (const float*)d_in[19];
    const float* ln2_g  = (const float*)d_in[20];
    const float* ln2_b  = (const float*)d_in[21];
    const float* w_ff1  = (const float*)d_in[22];
    const float* b_ff1  = (const float*)d_in[23];
    const float* w_ff2  = (const float*)d_in[24];
    const float* b_ff2  = (const float*)d_in[25];
    const float* pos_qx = (const float*)d_in[26];
    const float* pos_qy = (const float*)d_in[27];
    const float* pos_qz = (const float*)d_in[28];
    const float* pos_kx = (const float*)d_in[29];
    const float* pos_ky = (const float*)d_in[30];
    const float* pos_kz = (const float*)d_in[31];

    // workspace carve (~235 MB total)
    char* p = (char*)d_ws;
    auto take = [&](size_t n) { char* r = p; p += (n + 255) & ~(size_t)255; return r; };
    unsigned short* ln_x    = (unsigned short*)take((size_t)MV * CH * 2);   // 51.2 MB
    unsigned short* w_kv_t  = (unsigned short*)take((size_t)512 * 256 * 2); // 0.26 MB
    int*            flag    = (int*)take(256);
    int*            mask_i  = (int*)take((size_t)NG * 4);                   // 1.05 MB
    float*          qbuf    = (float*)take((size_t)NQ * CH * 4);            // 8.4 MB
    float*          qp      = (float*)take((size_t)NQ * QPN * 4);           // 9.7 MB
    unsigned short* kmat    = (unsigned short*)take((size_t)NG * CH * 2);   // 134 MB
    float*          attn    = (float*)take((size_t)NQ * 256 * 4);           // 8.4 MB
    float*          attnout = (float*)take((size_t)NQ * CH * 4);            // 8.4 MB
    float*          actbuf  = (float*)take((size_t)NQ * CH * 4);            // 8.4 MB
    unsigned short* actln   = (unsigned short*)take((size_t)NQ * CH * 2);   // 4.2 MB

    hipLaunchKernelGGL(k_detect_mask, dim3(1), dim3(256), 0, stream,
                       (const unsigned char*)mraw, flag);
    hipLaunchKernelGGL(k_prep, dim3(NG / 256), dim3(256), 0, stream,
                       w_k, w_v, mraw, flag, w_kv_t, mask_i);
    hipLaunchKernelGGL(k_ln1, dim3(MV / 4), dim3(256), 0, stream,
                       vox, ln1_g, ln1_b, ln_x);
    hipLaunchKernelGGL(k_q, dim3(NQ / 8), dim3(256), 0, stream,
                       ln_x, coords, qidx, w_pos, b_pos, w_q, b_q,
                       pos_qx, pos_qy, pos_qz, qbuf, qp);
    hipLaunchKernelGGL(HIP_KERNEL_NAME(k_gemm<0>), dim3(4, NG / 128), dim3(256), 0, stream,
                       ln_x, gidx, mask_i, w_kv_t, b_k, (const float*)nullptr,
                       kmat, (float*)nullptr);
    hipLaunchKernelGGL(k_attn, dim3(NQ / 4), dim3(256), 0, stream,
                       qbuf, qp, kmat, mask_i, rel_x, rel_y, rel_z,
                       pos_kx, pos_ky, pos_kz, attn);
    hipLaunchKernelGGL(HIP_KERNEL_NAME(k_gemm<1>), dim3(4, NG / 128), dim3(256), 0, stream,
                       ln_x, gidx, mask_i, w_kv_t, b_v, attn,
                       (unsigned short*)nullptr, attnout);
    hipLaunchKernelGGL(k_proj, dim3(NQ / 8), dim3(256), 0, stream,
                       attnout, w_proj, b_proj, vox, qidx, ln2_g, ln2_b,
                       actbuf, actln);
    hipLaunchKernelGGL(k_ff, dim3(NQ / 8), dim3(256), 0, stream,
                       actln, actbuf, w_ff1, b_ff1, w_ff2, b_ff2, (float*)d_out);
}

// Round 2
// 567.427 us; speedup vs baseline: 1.1554x; 1.1554x over previous
//
#include <hip/hip_runtime.h>
#include <hip/hip_bf16.h>
#include <math.h>

// Problem constants (fixed by the reference)
#define MV   100000          // voxels
#define NQ   8192            // queries
#define KN   32              // neighbors per query
#define CH   256             // channels
#define NH   8               // heads
#define DHD  32              // head dim
#define FFD  512             // FF hidden
#define NG   (NQ*KN)         // 262144 gathered rows
#define QPW  37              // 15+15+7 rel-pos columns per head (q-side)
#define QPN  (NH*QPW)        // 296

typedef __bf16 bf16x8 __attribute__((ext_vector_type(8)));
typedef float  f32x4  __attribute__((ext_vector_type(4)));

__device__ __forceinline__ float bf2f(unsigned short u) {
    return __uint_as_float(((unsigned int)u) << 16);
}
__device__ __forceinline__ unsigned short f2bf(float f) {
    unsigned int x = __float_as_uint(f);
    unsigned int r = x + 0x7FFFu + ((x >> 16) & 1u);   // RNE
    return (unsigned short)(r >> 16);
}

// ---------------------------------------------------------------------------
// k_detect_mask: gather_mask is bool in the reference; harness may ship it as
// int32 (0/1) or raw 1-byte bools. If int32, every byte at offset%4!=0 of the
// first NG bytes is zero. flag=1 -> byte layout, flag=0 -> int32 layout.
// ---------------------------------------------------------------------------
__global__ __launch_bounds__(256) void k_detect_mask(const unsigned char* __restrict__ raw,
                                                     int* __restrict__ flag) {
    __shared__ int any;
    if (threadIdx.x == 0) any = 0;
    __syncthreads();
    const uint4* p = (const uint4*)raw;
    int found = 0;
    for (int i = threadIdx.x; i < NG / 16; i += 256) {
        uint4 v = p[i];
        if ((v.x | v.y | v.z | v.w) & 0xFFFFFF00u) found = 1;
    }
    if (found) any = 1;
    __syncthreads();
    if (threadIdx.x == 0) flag[0] = any;
}

// ---------------------------------------------------------------------------
// k_prep: materialize int mask (layout-adaptive) + bf16 col-major (B-layout)
// transposed weights:
//   w_kv_t[512][256] : cols 0..255 = w_k cols, 256..511 = w_v cols
//   w1_t  [512][256] : w1_t[n][k] = w_ff1[k][n]
//   w2_t  [256][512] : w2_t[n][k] = w_ff2[k][n]
//   wp_t  [256][256] : wp_t[n][k] = w_proj[k][n]
// ---------------------------------------------------------------------------
__global__ __launch_bounds__(256) void k_prep(const float* __restrict__ w_k,
                                              const float* __restrict__ w_v,
                                              const float* __restrict__ w_ff1,
                                              const float* __restrict__ w_ff2,
                                              const float* __restrict__ w_proj,
                                              const void* __restrict__ mask_raw,
                                              const int* __restrict__ flag,
                                              unsigned short* __restrict__ w_kv_t,
                                              unsigned short* __restrict__ w1_t,
                                              unsigned short* __restrict__ w2_t,
                                              unsigned short* __restrict__ wp_t,
                                              int* __restrict__ mask_i) {
    int idx = blockIdx.x * 256 + threadIdx.x;       // grid 1024 -> 262144
    int byteLayout = flag[0];
    if (idx < NG) {
        int mv = byteLayout ? (int)((const unsigned char*)mask_raw)[idx]
                            : ((const int*)mask_raw)[idx];
        mask_i[idx] = (mv != 0) ? 1 : 0;
    }
    if (idx < 512 * 256) {
        int col = idx >> 8, j = idx & 255;
        float v = (col < 256) ? w_k[j * 256 + col] : w_v[j * 256 + (col - 256)];
        w_kv_t[idx] = f2bf(v);                      // idx == col*256 + j
    }
    if (idx < 512 * 256) {                          // w1_t[n][k], n=idx>>8, k=idx&255
        int n = idx >> 8, k = idx & 255;
        w1_t[idx] = f2bf(w_ff1[k * FFD + n]);
    }
    if (idx < 256 * 512) {                          // w2_t[n][k], n=idx>>9, k=idx&511
        int n = idx >> 9, k = idx & 511;
        w2_t[idx] = f2bf(w_ff2[k * CH + n]);
    }
    if (idx < 256 * 256) {                          // wp_t[n][k]
        int n = idx >> 8, k = idx & 255;
        wp_t[idx] = f2bf(w_proj[k * CH + n]);
    }
}

// ---------------------------------------------------------------------------
// k_ln: LayerNorm rows of x[nrows][256] -> bf16. One wave per row.
// ---------------------------------------------------------------------------
__global__ __launch_bounds__(256) void k_ln(const float* __restrict__ x,
                                            const float* __restrict__ g,
                                            const float* __restrict__ b,
                                            unsigned short* __restrict__ o,
                                            int nrows) {
    int wid = threadIdx.x >> 6, lane = threadIdx.x & 63;
    int row = blockIdx.x * 4 + wid;
    if (row >= nrows) return;
    const float4 v = *(const float4*)(x + (size_t)row * CH + lane * 4);
    float s  = v.x + v.y + v.z + v.w;
    float sq = v.x * v.x + v.y * v.y + v.z * v.z + v.w * v.w;
    #pragma unroll
    for (int off = 1; off < 64; off <<= 1) {
        s  += __shfl_xor(s,  off);
        sq += __shfl_xor(sq, off);
    }
    float mu  = s * (1.f / CH);
    float var = sq * (1.f / CH) - mu * mu;
    float rs  = rsqrtf(var + 1e-5f);
    float4 gv = *(const float4*)(g + lane * 4);
    float4 bv = *(const float4*)(b + lane * 4);
    ushort4 ov;
    ov.x = f2bf((v.x - mu) * rs * gv.x + bv.x);
    ov.y = f2bf((v.y - mu) * rs * gv.y + bv.y);
    ov.z = f2bf((v.z - mu) * rs * gv.z + bv.z);
    ov.w = f2bf((v.w - mu) * rs * gv.w + bv.w);
    *(ushort4*)(o + (size_t)row * CH + lane * 4) = ov;
}

// ---------------------------------------------------------------------------
// k_q: per 8-query block: q_in = ln_x[qi] + relu(coords@w_pos + b_pos);
// q = q_in@w_q + b_q (fp32); then q-side rel-pos table qp[n][h][37].
// ---------------------------------------------------------------------------
__global__ __launch_bounds__(256) void k_q(const unsigned short* __restrict__ ln_x,
                                           const float* __restrict__ coords,
                                           const int* __restrict__ qidx,
                                           const float* __restrict__ w_pos,
                                           const float* __restrict__ b_pos,
                                           const float* __restrict__ w_q,
                                           const float* __restrict__ b_q,
                                           const float* __restrict__ pos_qx,
                                           const float* __restrict__ pos_qy,
                                           const float* __restrict__ pos_qz,
                                           float* __restrict__ qout,
                                           float* __restrict__ qp) {
    __shared__ float qin_s[8 * CH];
    __shared__ float q_s[8 * CH];
    int c = threadIdx.x;
    int nb = blockIdx.x * 8;
    float wp0 = w_pos[c], wp1 = w_pos[CH + c], wp2 = w_pos[2 * CH + c], bp = b_pos[c];
    #pragma unroll
    for (int qq = 0; qq < 8; qq++) {
        int n = nb + qq;
        float p = bp + coords[n * 3] * wp0 + coords[n * 3 + 1] * wp1 + coords[n * 3 + 2] * wp2;
        p = fmaxf(p, 0.f);
        int qi = qidx[n];
        qin_s[qq * CH + c] = bf2f(ln_x[(size_t)qi * CH + c]) + p;
    }
    __syncthreads();
    float acc[8];
    float bq = b_q[c];
    #pragma unroll
    for (int qq = 0; qq < 8; qq++) acc[qq] = bq;
    #pragma unroll 4
    for (int j = 0; j < CH; j++) {
        float w = w_q[j * CH + c];
        #pragma unroll
        for (int qq = 0; qq < 8; qq++) acc[qq] += qin_s[qq * CH + j] * w;
    }
    #pragma unroll
    for (int qq = 0; qq < 8; qq++) {
        qout[(size_t)(nb + qq) * CH + c] = acc[qq];
        q_s[qq * CH + c] = acc[qq];
    }
    __syncthreads();
    for (int t = threadIdx.x; t < 8 * QPN; t += 256) {
        int qq = t / QPN, u = t % QPN;
        int h = u / QPW, r = u % QPW;
        const float* tab; int rr, R;
        if (r < 15)      { tab = pos_qx; rr = r;      R = 15; }
        else if (r < 30) { tab = pos_qy; rr = r - 15; R = 15; }
        else             { tab = pos_qz; rr = r - 30; R = 7;  }
        float a = 0.f;
        const float* qrow = q_s + qq * CH + h * DHD;
        #pragma unroll
        for (int d = 0; d < DHD; d++) a += qrow[d] * tab[(h * DHD + d) * R + rr];
        qp[(size_t)(nb + qq) * QPN + u] = a;
    }
}

// ---------------------------------------------------------------------------
// k_gemm<MODE>: gathered-row GEMM over the 262144 (n,k) rows.
//   MODE 0: store k = A@w_k + b_k as bf16 [NG][256]
//   MODE 1: epilogue attnout_bf[n][c] = bf16( sum_k attn[n,h(c),k]*v[k][c] + b_v[c] )
// Tile 128x64, 4 waves; wave w = query w's 32 neighbors in MODE 1.
// ---------------------------------------------------------------------------
template <int MODE>
__global__ __launch_bounds__(256) void k_gemm(const unsigned short* __restrict__ ln_x,
                                              const int* __restrict__ gidx,
                                              const int* __restrict__ mask_i,
                                              const unsigned short* __restrict__ w_kv_t,
                                              const float* __restrict__ bias,
                                              const float* __restrict__ attn,
                                              unsigned short* __restrict__ kout,
                                              unsigned short* __restrict__ attnout_bf) {
    __shared__ __align__(16) unsigned short As[128 * 32];   // row-major, stride 32
    __shared__ __align__(16) unsigned short Bt[64 * 40];    // col-major, stride 40
    __shared__ float attn_s[4 * 256];                       // MODE 1 only
    int tid = threadIdx.x;
    int w = tid >> 6, l = tid & 63;
    int rowbase = blockIdx.y * 128;
    int col0_w = blockIdx.x * 64 + (MODE ? 256 : 0);

    int r0 = tid >> 2, qt = tid & 3;
    int g0 = gidx[rowbase + r0];
    int m0 = mask_i[rowbase + r0];
    int g1 = gidx[rowbase + 64 + r0];
    int m1 = mask_i[rowbase + 64 + r0];
    const unsigned short* a0p = ln_x + (size_t)g0 * CH + qt * 8;
    const unsigned short* a1p = ln_x + (size_t)g1 * CH + qt * 8;

    if (MODE) {
        for (int i = tid; i < 1024; i += 256)
            attn_s[i] = attn[(size_t)blockIdx.y * 1024 + i];
    }

    f32x4 acc[2][4];
    #pragma unroll
    for (int mt = 0; mt < 2; mt++)
        #pragma unroll
        for (int nt = 0; nt < 4; nt++)
            acc[mt][nt] = (f32x4){0.f, 0.f, 0.f, 0.f};

    const int ml = l & 15, qd = l >> 4;
    const uint4 z4 = {0u, 0u, 0u, 0u};
    for (int kk = 0; kk < CH; kk += 32) {
        __syncthreads();
        uint4 v0 = m0 ? z4 : *(const uint4*)(a0p + kk);
        uint4 v1 = m1 ? z4 : *(const uint4*)(a1p + kk);
        *(uint4*)(As + tid * 8)        = v0;
        *(uint4*)(As + 2048 + tid * 8) = v1;
        {
            int cl = tid >> 2, sg = tid & 3;
            uint4 bv = *(const uint4*)(w_kv_t + (size_t)(col0_w + cl) * CH + kk + sg * 8);
            *(uint4*)(Bt + cl * 40 + sg * 8) = bv;
        }
        __syncthreads();
        bf16x8 a0 = *(const bf16x8*)(As + (w * 32 + ml) * 32 + qd * 8);
        bf16x8 a1 = *(const bf16x8*)(As + (w * 32 + 16 + ml) * 32 + qd * 8);
        #pragma unroll
        for (int nt = 0; nt < 4; nt++) {
            bf16x8 bb = *(const bf16x8*)(Bt + (nt * 16 + ml) * 40 + qd * 8);
            acc[0][nt] = __builtin_amdgcn_mfma_f32_16x16x32_bf16(a0, bb, acc[0][nt], 0, 0, 0);
            acc[1][nt] = __builtin_amdgcn_mfma_f32_16x16x32_bf16(a1, bb, acc[1][nt], 0, 0, 0);
        }
    }

    if (MODE == 0) {
        int colg0 = blockIdx.x * 64;
        #pragma unroll
        for (int nt = 0; nt < 4; nt++) {
            int col = colg0 + nt * 16 + ml;
            float bk = bias[col];
            #pragma unroll
            for (int mt = 0; mt < 2; mt++) {
                int rl = w * 32 + mt * 16 + qd * 4;
                #pragma unroll
                for (int i = 0; i < 4; i++)
                    kout[(size_t)(rowbase + rl + i) * CH + col] = f2bf(acc[mt][nt][i] + bk);
            }
        }
    } else {
        #pragma unroll
        for (int nt = 0; nt < 4; nt++) {
            int col = blockIdx.x * 64 + nt * 16 + ml;
            int h = col >> 5;
            float ps = 0.f;
            #pragma unroll
            for (int mt = 0; mt < 2; mt++)
                #pragma unroll
                for (int i = 0; i < 4; i++) {
                    int kkk = mt * 16 + qd * 4 + i;
                    ps += attn_s[w * 256 + (h << 5) + kkk] * acc[mt][nt][i];
                }
            ps += __shfl_xor(ps, 16);
            ps += __shfl_xor(ps, 32);
            if (qd == 0)
                attnout_bf[(size_t)(blockIdx.y * 4 + w) * CH + col] = f2bf(ps + bias[col]);
        }
    }
}

// ---------------------------------------------------------------------------
// k_mm<KD,EPI>: plain row GEMM, A[8192][KD] bf16 @ Bt[cols][KD] bf16.
// Tile 128x64, same skeleton as k_gemm.
//   EPI 0: relu -> bf16 store at ld FFD       (FF1: h = relu(x@w1+b1))
//   EPI 1: + bias + res[row][col] -> fp32 out (FF2: out = h@w2+b2+act)
//   EPI 2: + bias + res[qidx[row]][col] -> fp32 out (proj: act = o@wp+bp+vox[qi])
// ---------------------------------------------------------------------------
template <int KD, int EPI>
__global__ __launch_bounds__(256) void k_mm(const unsigned short* __restrict__ A,
                                            const unsigned short* __restrict__ Bt_g,
                                            const float* __restrict__ bias,
                                            const float* __restrict__ res,
                                            const int* __restrict__ qidx,
                                            unsigned short* __restrict__ out_bf,
                                            float* __restrict__ out_f) {
    __shared__ __align__(16) unsigned short As[128 * 32];
    __shared__ __align__(16) unsigned short Bs[64 * 40];
    int tid = threadIdx.x;
    int w = tid >> 6, l = tid & 63;
    int rowbase = blockIdx.y * 128;
    int col0 = blockIdx.x * 64;
    int r0 = tid >> 2, qt = tid & 3;
    const unsigned short* a0p = A + (size_t)(rowbase + r0) * KD + qt * 8;
    const unsigned short* a1p = A + (size_t)(rowbase + 64 + r0) * KD + qt * 8;

    f32x4 acc[2][4];
    #pragma unroll
    for (int mt = 0; mt < 2; mt++)
        #pragma unroll
        for (int nt = 0; nt < 4; nt++)
            acc[mt][nt] = (f32x4){0.f, 0.f, 0.f, 0.f};

    const int ml = l & 15, qd = l >> 4;
    for (int kk = 0; kk < KD; kk += 32) {
        __syncthreads();
        uint4 v0 = *(const uint4*)(a0p + kk);
        uint4 v1 = *(const uint4*)(a1p + kk);
        *(uint4*)(As + tid * 8)        = v0;
        *(uint4*)(As + 2048 + tid * 8) = v1;
        {
            int cl = tid >> 2, sg = tid & 3;
            uint4 bv = *(const uint4*)(Bt_g + (size_t)(col0 + cl) * KD + kk + sg * 8);
            *(uint4*)(Bs + cl * 40 + sg * 8) = bv;
        }
        __syncthreads();
        bf16x8 a0 = *(const bf16x8*)(As + (w * 32 + ml) * 32 + qd * 8);
        bf16x8 a1 = *(const bf16x8*)(As + (w * 32 + 16 + ml) * 32 + qd * 8);
        #pragma unroll
        for (int nt = 0; nt < 4; nt++) {
            bf16x8 bb = *(const bf16x8*)(Bs + (nt * 16 + ml) * 40 + qd * 8);
            acc[0][nt] = __builtin_amdgcn_mfma_f32_16x16x32_bf16(a0, bb, acc[0][nt], 0, 0, 0);
            acc[1][nt] = __builtin_amdgcn_mfma_f32_16x16x32_bf16(a1, bb, acc[1][nt], 0, 0, 0);
        }
    }

    #pragma unroll
    for (int nt = 0; nt < 4; nt++) {
        int col = col0 + nt * 16 + ml;
        float bv = bias[col];
        #pragma unroll
        for (int mt = 0; mt < 2; mt++) {
            int rl = w * 32 + mt * 16 + qd * 4;
            #pragma unroll
            for (int i = 0; i < 4; i++) {
                int row = rowbase + rl + i;
                float v = acc[mt][nt][i] + bv;
                if (EPI == 0) {
                    out_bf[(size_t)row * FFD + col] = f2bf(fmaxf(v, 0.f));
                } else if (EPI == 1) {
                    out_f[(size_t)row * CH + col] = v + res[(size_t)row * CH + col];
                } else {
                    int qi = qidx[row];
                    out_f[(size_t)row * CH + col] = v + res[(size_t)qi * CH + col];
                }
            }
        }
    }
}

// ---------------------------------------------------------------------------
// k_attn: logits = q.k * DH^-0.5 + q-side bias (gathered qp) + k-side bias;
// mask -> -1e9; softmax over K. 4 queries per block; thread = (h, k).
// ---------------------------------------------------------------------------
__global__ __launch_bounds__(256) void k_attn(const float* __restrict__ qbuf,
                                              const float* __restrict__ qp,
                                              const unsigned short* __restrict__ kmat,
                                              const int* __restrict__ mask_i,
                                              const int* __restrict__ rel_x,
                                              const int* __restrict__ rel_y,
                                              const int* __restrict__ rel_z,
                                              const float* __restrict__ pos_kx,
                                              const float* __restrict__ pos_ky,
                                              const float* __restrict__ pos_kz,
                                              float* __restrict__ attn) {
    __shared__ float pos_s[9472];     // [x:3840][y:3840][z:1792]
    __shared__ float q_s[1024];
    __shared__ float qp_s[4 * QPN];
    int tid = threadIdx.x;
    int qb = blockIdx.x * 4;
    for (int i = tid; i < 3840; i += 256) pos_s[i] = pos_kx[i];
    for (int i = tid; i < 3840; i += 256) pos_s[3840 + i] = pos_ky[i];
    for (int i = tid; i < 1792; i += 256) pos_s[7680 + i] = pos_kz[i];
    for (int i = tid; i < 1024; i += 256) q_s[i] = qbuf[(size_t)qb * CH + i];
    for (int i = tid; i < 4 * QPN; i += 256) qp_s[i] = qp[(size_t)qb * QPN + i];
    __syncthreads();
    int h = tid >> 5, k = tid & 31;
    const float scale = 0.17677669529663687f;   // 32^-0.5
    for (int qq = 0; qq < 4; qq++) {
        int n = qb + qq;
        int gi = n * KN + k;
        int mk = mask_i[gi];
        int rx = rel_x[gi], ry = rel_y[gi], rz = rel_z[gi];
        const uint4* kp = (const uint4*)(kmat + (size_t)gi * CH + h * DHD);
        float kv[32];
        #pragma unroll
        for (int j = 0; j < 4; j++) {
            uint4 u = kp[j];
            kv[j * 8 + 0] = bf2f((unsigned short)(u.x & 0xFFFF));
            kv[j * 8 + 1] = bf2f((unsigned short)(u.x >> 16));
            kv[j * 8 + 2] = bf2f((unsigned short)(u.y & 0xFFFF));
            kv[j * 8 + 3] = bf2f((unsigned short)(u.y >> 16));
            kv[j * 8 + 4] = bf2f((unsigned short)(u.z & 0xFFFF));
            kv[j * 8 + 5] = bf2f((unsigned short)(u.z >> 16));
            kv[j * 8 + 6] = bf2f((unsigned short)(u.w & 0xFFFF));
            kv[j * 8 + 7] = bf2f((unsigned short)(u.w >> 16));
        }
        float s1 = 0.f, s2 = 0.f;
        const float* qrow = q_s + qq * CH + h * DHD;
        const float* px = pos_s + h * 480 + rx;
        const float* py = pos_s + 3840 + h * 480 + ry;
        const float* pz = pos_s + 7680 + h * 224 + rz;
        #pragma unroll
        for (int d = 0; d < 32; d++) {
            s1 += kv[d] * qrow[d];
            s2 += kv[d] * (px[d * 15] + py[d * 15] + pz[d * 7]);
        }
        float lg = s1 * scale + s2
                 + qp_s[qq * QPN + h * QPW + rx]
                 + qp_s[qq * QPN + h * QPW + 15 + ry]
                 + qp_s[qq * QPN + h * QPW + 30 + rz];
        if (mk) lg = -1e9f;
        float mx = lg;
        #pragma unroll
        for (int off = 1; off <= 16; off <<= 1) mx = fmaxf(mx, __shfl_xor(mx, off));
        float e = __expf(lg - mx);
        float sm = e;
        #pragma unroll
        for (int off = 1; off <= 16; off <<= 1) sm += __shfl_xor(sm, off);
        attn[(size_t)n * 256 + tid] = e / sm;
    }
}

// ---------------------------------------------------------------------------
extern "C" void kernel_launch(void* const* d_in, const int* in_sizes, int n_in,
                              void* d_out, int out_size, void* d_ws, size_t ws_size,
                              hipStream_t stream) {
    (void)in_sizes; (void)n_in; (void)out_size; (void)ws_size;
    const float* vox    = (const float*)d_in[0];
    const float* coords = (const float*)d_in[1];
    const int*   qidx   = (const int*)d_in[2];
    const int*   gidx   = (const int*)d_in[3];
    const void*  mraw   = d_in[4];
    const int*   rel_x  = (const int*)d_in[5];
    const int*   rel_y  = (const int*)d_in[6];
    const int*   rel_z  = (const int*)d_in[7];
    const float* w_pos  = (const float*)d_in[8];
    const float* b_pos  = (const float*)d_in[9];
    const float* w_q    = (const float*)d_in[10];
    const float* b_q    = (const float*)d_in[11];
    const float* w_k    = (const float*)d_in[12];
    const float* b_k    = (const float*)d_in[13];
    const float* w_v    = (const float*)d_in[14];
    const float* b_v    = (const float*)d_in[15];
    const float* w_proj = (const float*)d_in[16];
    const float* b_proj = (const float*)d_in[17];
    const float* ln1_g  = (const float*)d_in[18];
    const float* ln1_b  = (const float*)d_in[19];
    const float* ln2_g  = (const float*)d_in[20];
    const float* ln2_b  = (const float*)d_in[21];
    const float* w_ff1  = (const float*)d_in[22];
    const float* b_ff1  = (const float*)d_in[23];
    const float* w_ff2  = (const float*)d_in[24];
    const float* b_ff2  = (const float*)d_in[25];
    const float* pos_qx = (const float*)d_in[26];
    const float* pos_qy = (const float*)d_in[27];
    const float* pos_qz = (const float*)d_in[28];
    const float* pos_kx = (const float*)d_in[29];
    const float* pos_ky = (const float*)d_in[30];
    const float* pos_kz = (const float*)d_in[31];

    // workspace carve (~240 MB total)
    char* p = (char*)d_ws;
    auto take = [&](size_t n) { char* r = p; p += (n + 255) & ~(size_t)255; return r; };
    unsigned short* ln_x    = (unsigned short*)take((size_t)MV * CH * 2);   // 51.2 MB
    unsigned short* w_kv_t  = (unsigned short*)take((size_t)512 * 256 * 2);
    unsigned short* w1_t    = (unsigned short*)take((size_t)512 * 256 * 2);
    unsigned short* w2_t    = (unsigned short*)take((size_t)256 * 512 * 2);
    unsigned short* wp_t    = (unsigned short*)take((size_t)256 * 256 * 2);
    int*            flag    = (int*)take(256);
    int*            mask_i  = (int*)take((size_t)NG * 4);                   // 1.05 MB
    float*          qbuf    = (float*)take((size_t)NQ * CH * 4);            // 8.4 MB
    float*          qp      = (float*)take((size_t)NQ * QPN * 4);           // 9.7 MB
    unsigned short* kmat    = (unsigned short*)take((size_t)NG * CH * 2);   // 134 MB
    float*          attn    = (float*)take((size_t)NQ * 256 * 4);           // 8.4 MB
    unsigned short* attnln  = (unsigned short*)take((size_t)NQ * CH * 2);   // 4.2 MB
    float*          actbuf  = (float*)take((size_t)NQ * CH * 4);            // 8.4 MB
    unsigned short* actln   = (unsigned short*)take((size_t)NQ * CH * 2);   // 4.2 MB
    unsigned short* hbuf    = (unsigned short*)take((size_t)NQ * FFD * 2);  // 8.4 MB

    hipLaunchKernelGGL(k_detect_mask, dim3(1), dim3(256), 0, stream,
                       (const unsigned char*)mraw, flag);
    hipLaunchKernelGGL(k_prep, dim3(NG / 256), dim3(256), 0, stream,
                       w_k, w_v, w_ff1, w_ff2, w_proj, mraw, flag,
                       w_kv_t, w1_t, w2_t, wp_t, mask_i);
    hipLaunchKernelGGL(k_ln, dim3(MV / 4 + 1), dim3(256), 0, stream,
                       vox, ln1_g, ln1_b, ln_x, MV);
    hipLaunchKernelGGL(k_q, dim3(NQ / 8), dim3(256), 0, stream,
                       ln_x, coords, qidx, w_pos, b_pos, w_q, b_q,
                       pos_qx, pos_qy, pos_qz, qbuf, qp);
    hipLaunchKernelGGL(HIP_KERNEL_NAME(k_gemm<0>), dim3(4, NG / 128), dim3(256), 0, stream,
                       ln_x, gidx, mask_i, w_kv_t, b_k, (const float*)nullptr,
                       kmat, (unsigned short*)nullptr);
    hipLaunchKernelGGL(k_attn, dim3(NQ / 4), dim3(256), 0, stream,
                       qbuf, qp, kmat, mask_i, rel_x, rel_y, rel_z,
                       pos_kx, pos_ky, pos_kz, attn);
    hipLaunchKernelGGL(HIP_KERNEL_NAME(k_gemm<1>), dim3(4, NG / 128), dim3(256), 0, stream,
                       ln_x, gidx, mask_i, w_kv_t, b_v, attn,
                       (unsigned short*)nullptr, attnln);
    // proj: act = attn_bf16 @ wp_t + b_proj + vox[qidx]
    hipLaunchKernelGGL(HIP_KERNEL_NAME(k_mm<256, 2>), dim3(4, NQ / 128), dim3(256), 0, stream,
                       attnln, wp_t, b_proj, vox, qidx,
                       (unsigned short*)nullptr, actbuf);
    hipLaunchKernelGGL(k_ln, dim3(NQ / 4), dim3(256), 0, stream,
                       actbuf, ln2_g, ln2_b, actln, NQ);
    // FF1: h = relu(actln @ w1_t + b_ff1)
    hipLaunchKernelGGL(HIP_KERNEL_NAME(k_mm<256, 0>), dim3(8, NQ / 128), dim3(256), 0, stream,
                       actln, w1_t, b_ff1, (const float*)nullptr, (const int*)nullptr,
                       hbuf, (float*)nullptr);
    // FF2: out = h @ w2_t + b_ff2 + act
    hipLaunchKernelGGL(HIP_KERNEL_NAME(k_mm<512, 1>), dim3(4, NQ / 128), dim3(256), 0, stream,
                       hbuf, w2_t, b_ff2, actbuf, (const int*)nullptr,
                       (unsigned short*)nullptr, (float*)d_out);
}